// Round 1
// baseline (1798.980 us; speedup 1.0000x reference)
//
#include <hip/hip_runtime.h>
#include <hip/hip_bf16.h>

typedef __attribute__((ext_vector_type(8))) short bf16x8;
typedef __attribute__((ext_vector_type(4))) float f32x4;
typedef __attribute__((ext_vector_type(4))) unsigned short u16x4;

#define HB 256      // hidden
#define G3 768      // 3*H
#define SQ 512      // seq len
#define NBATCH 4
#define NV 32000

__device__ __forceinline__ unsigned short f2bf(float f) {
    unsigned int u = __float_as_uint(f);
    u = u + 0x7FFFu + ((u >> 16) & 1u);   // RNE
    return (unsigned short)(u >> 16);
}
__device__ __forceinline__ float sigm(float x) {
    return 1.0f / (1.0f + __expf(-x));
}
__device__ __forceinline__ float tanh_fast(float x) {
    // safe at +/-inf: 1 - 2/(e^{2x}+1)
    return 1.0f - 2.0f / (__expf(2.0f * x) + 1.0f);
}

// ---------------------------------------------------------------- K0: prep
// (a) W_ih^T fp32 [256][768] for coalesced K1 loads
// (b) W_hh -> bf16 MFMA A-fragment order for K2
// (c) W_out -> bf16 (optional, if ws large enough)
__global__ void k_prep(const float* __restrict__ W_ih, const float* __restrict__ W_hh,
                       const float* __restrict__ W_out, float* __restrict__ w_ihT,
                       unsigned short* __restrict__ wfrag, unsigned short* __restrict__ woutbf,
                       int do_wout) {
    int stride = gridDim.x * blockDim.x;
    int tid = blockIdx.x * blockDim.x + threadIdx.x;
    for (int e = tid; e < G3 * HB; e += stride) {
        int k = e / G3, g = e - k * G3;
        w_ihT[e] = W_ih[g * HB + k];
    }
    // frag element e = ((w*6+t)*8+c)*512 + l*8 + i
    for (int e = tid; e < G3 * HB; e += stride) {
        int i = e & 7, l = (e >> 3) & 63, c = (e >> 9) & 7, r = e >> 12;
        int t = r % 6, w = r / 6;
        int row = (t >> 1) * 256 + 32 * w + 16 * (t & 1) + (l & 15);
        int kk = 32 * c + 8 * (l >> 4) + i;
        wfrag[e] = f2bf(W_hh[row * HB + kk]);
    }
    if (do_wout) {
        for (int e = tid; e < NV * HB; e += stride) woutbf[e] = f2bf(W_out[e]);
    }
}

// ---------------------------------------------------------------- K1: embed + xp
// xp[tok][g] = sum_h emb[x[tok]][h] * W_ih[g][h] + b_ih[g] (+ b_hh[g] folded for r,z)
// 256 blocks x 256 thr; 8 tokens per block; W_ih^T so lane loads are coalesced;
// emb rows in LDS read at wave-uniform addresses (broadcast, conflict-free).
__global__ __launch_bounds__(256) void k_embed_xp(
        const int* __restrict__ x, const float* __restrict__ emb,
        const float* __restrict__ w_ihT, const float* __restrict__ b_ih,
        const float* __restrict__ b_hh, float* __restrict__ xp) {
    __shared__ float e[8][HB];
    int tid = threadIdx.x;
    int tok0 = blockIdx.x * 8;
    {
        int s = tid >> 5, k0 = (tid & 31) * 8;
        long idx = x[tok0 + s];
        const float* src = emb + idx * (long)HB + k0;
        f32x4 a = *(const f32x4*)src, bq = *(const f32x4*)(src + 4);
        *(f32x4*)&e[s][k0] = a;
        *(f32x4*)&e[s][k0 + 4] = bq;
    }
    __syncthreads();
    #pragma unroll
    for (int it = 0; it < 3; ++it) {
        int gg = tid + it * 256;
        float acc[8] = {0.f, 0.f, 0.f, 0.f, 0.f, 0.f, 0.f, 0.f};
        for (int k = 0; k < HB; k += 4) {
            float w0 = w_ihT[(k + 0) * G3 + gg];
            float w1 = w_ihT[(k + 1) * G3 + gg];
            float w2 = w_ihT[(k + 2) * G3 + gg];
            float w3 = w_ihT[(k + 3) * G3 + gg];
            #pragma unroll
            for (int s = 0; s < 8; ++s) {
                f32x4 ev = *(const f32x4*)&e[s][k];
                acc[s] += w0 * ev.x + w1 * ev.y + w2 * ev.z + w3 * ev.w;
            }
        }
        float bias = b_ih[gg] + (gg < 512 ? b_hh[gg] : 0.f);
        #pragma unroll
        for (int s = 0; s < 8; ++s)
            xp[(size_t)(tok0 + s) * G3 + gg] = acc[s] + bias;
    }
}

// ---------------------------------------------------------------- K2: GRU scan
// One workgroup, 8 waves. Wave w owns hidden indices i in [32w, 32w+32) for all 3
// gates: 6 MFMA row-tiles (r0,r1,z0,z1,n0,n1). W_hh lives in registers as 48
// bf16 A-fragments per lane (192 VGPRs). h broadcast through double-buffered
// bf16 LDS; one barrier per step.
__global__ __launch_bounds__(512, 2) void k_gru(
        const float* __restrict__ xp, const unsigned short* __restrict__ wfrag,
        const float* __restrict__ b_hh, unsigned short* __restrict__ rnn) {
    __shared__ unsigned short h_bf[2][NBATCH][HB];   // 4 KB
    __shared__ float bn_lds[HB];                     // 1 KB (b_hh n-gate)
    int tid = threadIdx.x;
    int w = tid >> 6, l = tid & 63;
    int b = l & 15, hi = l >> 4;

    // load the 48 A-fragments (perfectly coalesced: lane-contiguous 16B units)
    bf16x8 A[6][8];
    #pragma unroll
    for (int t6 = 0; t6 < 6; ++t6)
        #pragma unroll
        for (int c = 0; c < 8; ++c)
            A[t6][c] = ((const bf16x8*)wfrag)[((w * 6 + t6) * 8 + c) * 64 + l];

    for (int k = tid; k < 2 * NBATCH * HB; k += 512) ((unsigned short*)h_bf)[k] = 0;
    for (int k = tid; k < HB; k += 512) bn_lds[k] = b_hh[512 + k];
    __syncthreads();

    float hold[8] = {0.f, 0.f, 0.f, 0.f, 0.f, 0.f, 0.f, 0.f};
    const int i0 = 32 * w + 4 * hi;                  // + 16*ti for second subtile
    const f32x4 zz = {0.f, 0.f, 0.f, 0.f};

    for (int t = 0; t < SQ; ++t) {
        const float* xpt = xp + ((size_t)(b & 3) * SQ + t) * G3 + i0;
        // prefetch r/z xp rows (hidden under MFMA phase)
        f32x4 xr0 = *(const f32x4*)(xpt);
        f32x4 xr1 = *(const f32x4*)(xpt + 16);
        f32x4 xz0 = *(const f32x4*)(xpt + 256);
        f32x4 xz1 = *(const f32x4*)(xpt + 256 + 16);

        f32x4 acc[6];
        #pragma unroll
        for (int t6 = 0; t6 < 6; ++t6) acc[t6] = zz;

        const unsigned short* hb = &h_bf[t & 1][b & 3][0];
        #pragma unroll
        for (int c = 0; c < 8; ++c) {
            bf16x8 Bf = *(const bf16x8*)(hb + 32 * c + 8 * hi);
            #pragma unroll
            for (int t6 = 0; t6 < 6; ++t6)
                acc[t6] = __builtin_amdgcn_mfma_f32_16x16x32_bf16(A[t6][c], Bf, acc[t6], 0, 0, 0);
        }

        if (b < 4) {
            f32x4 xn0 = *(const f32x4*)(xpt + 512);
            f32x4 xn1 = *(const f32x4*)(xpt + 512 + 16);
            f32x4 bn0 = *(const f32x4*)(&bn_lds[i0]);
            f32x4 bn1 = *(const f32x4*)(&bn_lds[i0 + 16]);
            unsigned short* rr = rnn + ((size_t)b * SQ + t) * HB + i0;
            {   // ti = 0
                u16x4 pack;
                #pragma unroll
                for (int j = 0; j < 4; ++j) {
                    float r = sigm(xr0[j] + acc[0][j]);
                    float z = sigm(xz0[j] + acc[2][j]);
                    float n = tanh_fast(xn0[j] + r * (acc[4][j] + bn0[j]));
                    float hv = (1.f - z) * n + z * hold[j];
                    hold[j] = hv;
                    pack[j] = f2bf(hv);
                }
                *(u16x4*)&h_bf[(t + 1) & 1][b][i0] = pack;
                *(u16x4*)rr = pack;
            }
            {   // ti = 1
                u16x4 pack;
                #pragma unroll
                for (int j = 0; j < 4; ++j) {
                    float r = sigm(xr1[j] + acc[1][j]);
                    float z = sigm(xz1[j] + acc[3][j]);
                    float n = tanh_fast(xn1[j] + r * (acc[5][j] + bn1[j]));
                    float hv = (1.f - z) * n + z * hold[4 + j];
                    hold[4 + j] = hv;
                    pack[j] = f2bf(hv);
                }
                *(u16x4*)&h_bf[(t + 1) & 1][b][i0 + 16] = pack;
                *(u16x4*)(rr + 16) = pack;
            }
        }
        __syncthreads();   // single barrier/step: buffers double-buffered
    }
}

// ---------------------------------------------------------------- K3: logits
// [2048,256] bf16 @ [256,32000] bf16 -> fp32 + bias + mask. No LDS: A (1 MB)
// and B (16 MB) are L2/L3 resident; HBM-write-bound.
template <int CONV>
__global__ __launch_bounds__(256) void k_logits(
        const unsigned short* __restrict__ rnn, const unsigned short* __restrict__ woutbf,
        const float* __restrict__ woutf, const float* __restrict__ b_out,
        const int* __restrict__ x, float* __restrict__ out) {
    int tid = threadIdx.x;
    int wv = tid >> 6, l = tid & 63;
    int wm = wv >> 1, wn = wv & 1;
    int c15 = l & 15, hi = l >> 4;
    int m0 = blockIdx.y * 128 + wm * 64;
    int n0 = blockIdx.x * 128 + wn * 64;

    const f32x4 zz = {0.f, 0.f, 0.f, 0.f};
    f32x4 acc[4][4];
    #pragma unroll
    for (int i = 0; i < 4; ++i)
        #pragma unroll
        for (int j = 0; j < 4; ++j) acc[i][j] = zz;

    #pragma unroll
    for (int c = 0; c < 8; ++c) {
        bf16x8 af[4], bfr[4];
        #pragma unroll
        for (int rt = 0; rt < 4; ++rt)
            af[rt] = *(const bf16x8*)(rnn + (size_t)(m0 + rt * 16 + c15) * HB + 32 * c + 8 * hi);
        #pragma unroll
        for (int ct = 0; ct < 4; ++ct) {
            if (CONV) {
                const float* s = woutf + (size_t)(n0 + ct * 16 + c15) * HB + 32 * c + 8 * hi;
                f32x4 lo = *(const f32x4*)s, hi4 = *(const f32x4*)(s + 4);
                bf16x8 bb;
                #pragma unroll
                for (int q = 0; q < 4; ++q) bb[q] = (short)f2bf(lo[q]);
                #pragma unroll
                for (int q = 0; q < 4; ++q) bb[4 + q] = (short)f2bf(hi4[q]);
                bfr[ct] = bb;
            } else {
                bfr[ct] = *(const bf16x8*)(woutbf + (size_t)(n0 + ct * 16 + c15) * HB + 32 * c + 8 * hi);
            }
        }
        #pragma unroll
        for (int rt = 0; rt < 4; ++rt)
            #pragma unroll
            for (int ct = 0; ct < 4; ++ct)
                acc[rt][ct] = __builtin_amdgcn_mfma_f32_16x16x32_bf16(af[rt], bfr[ct], acc[rt][ct], 0, 0, 0);
    }

    float bo[4];
    #pragma unroll
    for (int ct = 0; ct < 4; ++ct) bo[ct] = b_out[n0 + ct * 16 + c15];

    const float NEGINF = -__builtin_inff();
    #pragma unroll
    for (int rt = 0; rt < 4; ++rt) {
        #pragma unroll
        for (int j = 0; j < 4; ++j) {
            int m = m0 + rt * 16 + 4 * hi + j;
            int tt = m & (SQ - 1);
            bool bad = (tt > 0) && (x[m - 1] == 0);
            float* orow = out + (size_t)m * NV;
            #pragma unroll
            for (int ct = 0; ct < 4; ++ct) {
                int v = n0 + ct * 16 + c15;
                float val = acc[rt][ct][j] + bo[ct];
                if (bad && v >= 3) val = NEGINF;
                orow[v] = val;
            }
        }
    }
}

extern "C" void kernel_launch(void* const* d_in, const int* in_sizes, int n_in,
                              void* d_out, int out_size, void* d_ws, size_t ws_size,
                              hipStream_t stream) {
    const int*   x     = (const int*)d_in[0];
    const float* emb   = (const float*)d_in[1];
    const float* W_ih  = (const float*)d_in[2];
    const float* W_hh  = (const float*)d_in[3];
    const float* b_ih  = (const float*)d_in[4];
    const float* b_hh  = (const float*)d_in[5];
    const float* W_out = (const float*)d_in[6];
    const float* b_out = (const float*)d_in[7];
    float* out = (float*)d_out;

    char* ws = (char*)d_ws;
    float*          xp     = (float*)(ws);                       // 6,291,456 B
    float*          w_ihT  = (float*)(ws + 6291456);             // 786,432 B
    unsigned short* wfrag  = (unsigned short*)(ws + 7077888);    // 393,216 B
    unsigned short* rnn    = (unsigned short*)(ws + 7471104);    // 1,048,576 B
    unsigned short* woutbf = (unsigned short*)(ws + 8519680);    // 16,384,000 B
    int use_woutbf = (ws_size >= (size_t)24903680) ? 1 : 0;

    k_prep<<<2048, 256, 0, stream>>>(W_ih, W_hh, W_out, w_ihT, wfrag, woutbf, use_woutbf);
    k_embed_xp<<<256, 256, 0, stream>>>(x, emb, w_ihT, b_ih, b_hh, xp);
    k_gru<<<1, 512, 0, stream>>>(xp, wfrag, b_hh, rnn);
    dim3 g3(NV / 128, 2048 / 128);
    if (use_woutbf)
        k_logits<0><<<g3, 256, 0, stream>>>(rnn, woutbf, nullptr, b_out, x, out);
    else
        k_logits<1><<<g3, 256, 0, stream>>>(rnn, nullptr, W_out, b_out, x, out);
}

// Round 2
// 1032.633 us; speedup vs baseline: 1.7421x; 1.7421x over previous
//
#include <hip/hip_runtime.h>
#include <hip/hip_bf16.h>

typedef __attribute__((ext_vector_type(8))) short bf16x8;
typedef __attribute__((ext_vector_type(4))) float f32x4;
typedef __attribute__((ext_vector_type(4))) unsigned short u16x4;

#define HB 256      // hidden
#define G3 768      // 3*H
#define SQ 512      // seq len
#define NBATCH 4
#define NV 32000

__device__ __forceinline__ unsigned short f2bf(float f) {
    unsigned int u = __float_as_uint(f);
    u = u + 0x7FFFu + ((u >> 16) & 1u);   // RNE
    return (unsigned short)(u >> 16);
}
__device__ __forceinline__ float sigm(float x) {
    return 1.0f / (1.0f + __expf(-x));
}
__device__ __forceinline__ float tanh_fast(float x) {
    // safe at +/-inf: 1 - 2/(e^{2x}+1)
    return 1.0f - 2.0f / (__expf(2.0f * x) + 1.0f);
}

// ---------------------------------------------------------------- K0: prep
// (a) W_ih^T fp32 [256][768] for coalesced K1 loads
// (b) W_hh -> bf16 MFMA A-fragment order for K2 (16-wave layout:
//     wave w owns hidden rows 16w..16w+15 for each of the 3 gates)
// (c) W_out -> bf16 (optional, if ws large enough)
__global__ void k_prep(const float* __restrict__ W_ih, const float* __restrict__ W_hh,
                       const float* __restrict__ W_out, float* __restrict__ w_ihT,
                       unsigned short* __restrict__ wfrag, unsigned short* __restrict__ woutbf,
                       int do_wout) {
    int stride = gridDim.x * blockDim.x;
    int tid = blockIdx.x * blockDim.x + threadIdx.x;
    for (int e = tid; e < G3 * HB; e += stride) {
        int k = e / G3, g = e - k * G3;
        w_ihT[e] = W_ih[g * HB + k];
    }
    // frag element e = ((w*3+t)*8+c)*512 + l*8 + i   (w: wave 0..15, t: gate 0..2)
    for (int e = tid; e < G3 * HB; e += stride) {
        int i = e & 7, l = (e >> 3) & 63, c = (e >> 9) & 7, r = e >> 12; // r in [0,48)
        int t = r % 3, w = r / 3;
        int row = t * 256 + 16 * w + (l & 15);
        int kk = 32 * c + 8 * (l >> 4) + i;
        wfrag[e] = f2bf(W_hh[row * HB + kk]);
    }
    if (do_wout) {
        for (int e = tid; e < NV * HB; e += stride) woutbf[e] = f2bf(W_out[e]);
    }
}

// ---------------------------------------------------------------- K1: embed + xp
__global__ __launch_bounds__(256) void k_embed_xp(
        const int* __restrict__ x, const float* __restrict__ emb,
        const float* __restrict__ w_ihT, const float* __restrict__ b_ih,
        const float* __restrict__ b_hh, float* __restrict__ xp) {
    __shared__ float e[8][HB];
    int tid = threadIdx.x;
    int tok0 = blockIdx.x * 8;
    {
        int s = tid >> 5, k0 = (tid & 31) * 8;
        long idx = x[tok0 + s];
        const float* src = emb + idx * (long)HB + k0;
        f32x4 a = *(const f32x4*)src, bq = *(const f32x4*)(src + 4);
        *(f32x4*)&e[s][k0] = a;
        *(f32x4*)&e[s][k0 + 4] = bq;
    }
    __syncthreads();
    #pragma unroll
    for (int it = 0; it < 3; ++it) {
        int gg = tid + it * 256;
        float acc[8] = {0.f, 0.f, 0.f, 0.f, 0.f, 0.f, 0.f, 0.f};
        for (int k = 0; k < HB; k += 4) {
            float w0 = w_ihT[(k + 0) * G3 + gg];
            float w1 = w_ihT[(k + 1) * G3 + gg];
            float w2 = w_ihT[(k + 2) * G3 + gg];
            float w3 = w_ihT[(k + 3) * G3 + gg];
            #pragma unroll
            for (int s = 0; s < 8; ++s) {
                f32x4 ev = *(const f32x4*)&e[s][k];
                acc[s] += w0 * ev.x + w1 * ev.y + w2 * ev.z + w3 * ev.w;
            }
        }
        float bias = b_ih[gg] + (gg < 512 ? b_hh[gg] : 0.f);
        #pragma unroll
        for (int s = 0; s < 8; ++s)
            xp[(size_t)(tok0 + s) * G3 + gg] = acc[s] + bias;
    }
}

// ---------------------------------------------------------------- K2: GRU scan
// One workgroup, 16 waves, 1024 threads. Wave w owns hidden rows 16w..16w+15
// for all 3 gates: A[3][8] bf16 fragments = 96 VGPR/lane (fits 128 budget at
// 4 waves/SIMD -> no spill). Two phases per step:
//   phase 1 (waves): 24 MFMA -> hp[4][784] in LDS (pad => 2-way banks, free)
//   phase 2 (threads as (b,i)): gate math, h_prev in a register, h -> swizzled
//   bf16 LDS buffer + global rnn.
__global__ __launch_bounds__(1024) void k_gru(
        const float* __restrict__ xp, const unsigned short* __restrict__ wfrag,
        const float* __restrict__ b_hh, unsigned short* __restrict__ rnn) {
    __shared__ unsigned short h_bf[2][NBATCH][HB];   // 4 KB, XOR-swizzled (^ (b&1)<<6)
    __shared__ float hp[NBATCH][784];                // 12.25 KB, padded rows

    int tid = threadIdx.x;
    int w = tid >> 6, l = tid & 63;
    int c15 = l & 15, hi = l >> 4;
    int b4 = c15 & 3;

    // 24 A-fragments, lane-contiguous 16B global loads (coalesced)
    bf16x8 A[3][8];
    #pragma unroll
    for (int t3 = 0; t3 < 3; ++t3)
        #pragma unroll
        for (int c = 0; c < 8; ++c)
            A[t3][c] = ((const bf16x8*)wfrag)[((w * 3 + t3) * 8 + c) * 64 + l];

    // gate-thread identity: b = tid>>8, i = tid&255
    int gb = tid >> 8;
    int gi = tid & 255;
    float bn = b_hh[512 + gi];
    float hreg = 0.f;

    for (int k = tid; k < 2 * NBATCH * HB; k += 1024) ((unsigned short*)h_bf)[k] = 0;
    __syncthreads();

    const f32x4 zz = {0.f, 0.f, 0.f, 0.f};
    const char* hbase = (const char*)&h_bf[0][0][0];
    int boff = b4 * 512;                      // byte offset of batch row
    int hrow0 = 16 * w + 4 * hi;              // hp row base (gate 0)

    for (int t = 0; t < SQ; ++t) {
        int cur = t & 1, nxt = cur ^ 1;
        // prefetch xp for phase 2 (in flight across the MFMA phase)
        const float* xpt = xp + ((size_t)gb * SQ + t) * G3 + gi;
        float xr = xpt[0], xz = xpt[256], xn = xpt[512];

        f32x4 acc0 = zz, acc1 = zz, acc2 = zz;
        const char* hb = hbase + cur * 2048 + boff;
        #pragma unroll
        for (int c = 0; c < 8; ++c) {
            int byteoff = (64 * c + 16 * hi) ^ ((c15 & 1) << 6);
            bf16x8 Bf = *(const bf16x8*)(hb + byteoff);
            acc0 = __builtin_amdgcn_mfma_f32_16x16x32_bf16(A[0][c], Bf, acc0, 0, 0, 0);
            acc1 = __builtin_amdgcn_mfma_f32_16x16x32_bf16(A[1][c], Bf, acc1, 0, 0, 0);
            acc2 = __builtin_amdgcn_mfma_f32_16x16x32_bf16(A[2][c], Bf, acc2, 0, 0, 0);
        }
        if (c15 < 4) {
            *(f32x4*)&hp[c15][hrow0]       = acc0;
            *(f32x4*)&hp[c15][256 + hrow0] = acc1;
            *(f32x4*)&hp[c15][512 + hrow0] = acc2;
        }
        __syncthreads();

        // phase 2: gate math, fully parallel over (b,i)
        float r = sigm(xr + hp[gb][gi]);
        float z = sigm(xz + hp[gb][256 + gi]);
        float n = tanh_fast(xn + r * (hp[gb][512 + gi] + bn));
        float hv = (1.f - z) * n + z * hreg;
        hreg = hv;
        unsigned short h16 = f2bf(hv);
        *(unsigned short*)((char*)&h_bf[nxt][gb][0] + ((gi * 2) ^ ((gb & 1) << 6))) = h16;
        rnn[((size_t)gb * SQ + t) * HB + gi] = h16;
        __syncthreads();
    }
}

// ---------------------------------------------------------------- K3: logits
// [2048,256] bf16 @ [256,32000] bf16 -> fp32 + bias + mask. No LDS: A (1 MB)
// and B (16 MB) are L2/L3 resident; HBM-write-bound.
template <int CONV>
__global__ __launch_bounds__(256) void k_logits(
        const unsigned short* __restrict__ rnn, const unsigned short* __restrict__ woutbf,
        const float* __restrict__ woutf, const float* __restrict__ b_out,
        const int* __restrict__ x, float* __restrict__ out) {
    int tid = threadIdx.x;
    int wv = tid >> 6, l = tid & 63;
    int wm = wv >> 1, wn = wv & 1;
    int c15 = l & 15, hi = l >> 4;
    int m0 = blockIdx.y * 128 + wm * 64;
    int n0 = blockIdx.x * 128 + wn * 64;

    const f32x4 zz = {0.f, 0.f, 0.f, 0.f};
    f32x4 acc[4][4];
    #pragma unroll
    for (int i = 0; i < 4; ++i)
        #pragma unroll
        for (int j = 0; j < 4; ++j) acc[i][j] = zz;

    #pragma unroll
    for (int c = 0; c < 8; ++c) {
        bf16x8 af[4], bfr[4];
        #pragma unroll
        for (int rt = 0; rt < 4; ++rt)
            af[rt] = *(const bf16x8*)(rnn + (size_t)(m0 + rt * 16 + c15) * HB + 32 * c + 8 * hi);
        #pragma unroll
        for (int ct = 0; ct < 4; ++ct) {
            if (CONV) {
                const float* s = woutf + (size_t)(n0 + ct * 16 + c15) * HB + 32 * c + 8 * hi;
                f32x4 lo = *(const f32x4*)s, hi4 = *(const f32x4*)(s + 4);
                bf16x8 bb;
                #pragma unroll
                for (int q = 0; q < 4; ++q) bb[q] = (short)f2bf(lo[q]);
                #pragma unroll
                for (int q = 0; q < 4; ++q) bb[4 + q] = (short)f2bf(hi4[q]);
                bfr[ct] = bb;
            } else {
                bfr[ct] = *(const bf16x8*)(woutbf + (size_t)(n0 + ct * 16 + c15) * HB + 32 * c + 8 * hi);
            }
        }
        #pragma unroll
        for (int rt = 0; rt < 4; ++rt)
            #pragma unroll
            for (int ct = 0; ct < 4; ++ct)
                acc[rt][ct] = __builtin_amdgcn_mfma_f32_16x16x32_bf16(af[rt], bfr[ct], acc[rt][ct], 0, 0, 0);
    }

    float bo[4];
    #pragma unroll
    for (int ct = 0; ct < 4; ++ct) bo[ct] = b_out[n0 + ct * 16 + c15];

    const float NEGINF = -__builtin_inff();
    #pragma unroll
    for (int rt = 0; rt < 4; ++rt) {
        #pragma unroll
        for (int j = 0; j < 4; ++j) {
            int m = m0 + rt * 16 + 4 * hi + j;
            int tt = m & (SQ - 1);
            bool bad = (tt > 0) && (x[m - 1] == 0);
            float* orow = out + (size_t)m * NV;
            #pragma unroll
            for (int ct = 0; ct < 4; ++ct) {
                int v = n0 + ct * 16 + c15;
                float val = acc[rt][ct][j] + bo[ct];
                if (bad && v >= 3) val = NEGINF;
                orow[v] = val;
            }
        }
    }
}

extern "C" void kernel_launch(void* const* d_in, const int* in_sizes, int n_in,
                              void* d_out, int out_size, void* d_ws, size_t ws_size,
                              hipStream_t stream) {
    const int*   x     = (const int*)d_in[0];
    const float* emb   = (const float*)d_in[1];
    const float* W_ih  = (const float*)d_in[2];
    const float* W_hh  = (const float*)d_in[3];
    const float* b_ih  = (const float*)d_in[4];
    const float* b_hh  = (const float*)d_in[5];
    const float* W_out = (const float*)d_in[6];
    const float* b_out = (const float*)d_in[7];
    float* out = (float*)d_out;

    char* ws = (char*)d_ws;
    float*          xp     = (float*)(ws);                       // 6,291,456 B
    float*          w_ihT  = (float*)(ws + 6291456);             // 786,432 B
    unsigned short* wfrag  = (unsigned short*)(ws + 7077888);    // 393,216 B
    unsigned short* rnn    = (unsigned short*)(ws + 7471104);    // 1,048,576 B
    unsigned short* woutbf = (unsigned short*)(ws + 8519680);    // 16,384,000 B
    int use_woutbf = (ws_size >= (size_t)24903680) ? 1 : 0;

    k_prep<<<2048, 256, 0, stream>>>(W_ih, W_hh, W_out, w_ihT, wfrag, woutbf, use_woutbf);
    k_embed_xp<<<256, 256, 0, stream>>>(x, emb, w_ihT, b_ih, b_hh, xp);
    k_gru<<<1, 1024, 0, stream>>>(xp, wfrag, b_hh, rnn);
    dim3 g3(NV / 128, 2048 / 128);
    if (use_woutbf)
        k_logits<0><<<g3, 256, 0, stream>>>(rnn, woutbf, nullptr, b_out, x, out);
    else
        k_logits<1><<<g3, 256, 0, stream>>>(rnn, nullptr, W_out, b_out, x, out);
}

// Round 3
// 995.897 us; speedup vs baseline: 1.8064x; 1.0369x over previous
//
#include <hip/hip_runtime.h>
#include <hip/hip_bf16.h>

typedef __attribute__((ext_vector_type(8))) short bf16x8;
typedef __attribute__((ext_vector_type(4))) float f32x4;
typedef __attribute__((ext_vector_type(4))) unsigned short u16x4;

#define HB 256      // hidden
#define G3 768      // 3*H
#define SQ 512      // seq len
#define NBATCH 4
#define NV 32000

// k_gru LDS carve (dynamic): wn 131072 | hp 12544 | h_bf 4096  = 147712 B
#define GRU_LDS_BYTES 147712

__device__ __forceinline__ unsigned short f2bf(float f) {
    unsigned int u = __float_as_uint(f);
    u = u + 0x7FFFu + ((u >> 16) & 1u);   // RNE
    return (unsigned short)(u >> 16);
}
__device__ __forceinline__ float sigm(float x) {
    return 1.0f / (1.0f + __expf(-x));
}
__device__ __forceinline__ float tanh_fast(float x) {
    // safe at +/-inf: 1 - 2/(e^{2x}+1)
    return 1.0f - 2.0f / (__expf(2.0f * x) + 1.0f);
}

// ---------------------------------------------------------------- K0: prep
// (a) W_ih^T fp32 [256][768] for coalesced K1 loads
// (b) W_hh -> bf16 MFMA A-fragments, split:
//     rz part  [w:16][t:2][c:8][lane:64][i:8]  (reg-resident in k_gru)
//     n  part  [w:16][c:8][lane:64][i:8]       (LDS-streamed in k_gru)
// (c) W_out -> bf16 (optional, if ws large enough)
__global__ void k_prep(const float* __restrict__ W_ih, const float* __restrict__ W_hh,
                       const float* __restrict__ W_out, float* __restrict__ w_ihT,
                       unsigned short* __restrict__ wfrag, unsigned short* __restrict__ woutbf,
                       int do_wout) {
    int stride = gridDim.x * blockDim.x;
    int tid = blockIdx.x * blockDim.x + threadIdx.x;
    for (int e = tid; e < G3 * HB; e += stride) {
        int k = e / G3, g = e - k * G3;
        w_ihT[e] = W_ih[g * HB + k];
    }
    // rz part: e in [0, 131072)
    for (int e = tid; e < 2 * HB * HB; e += stride) {
        int i = e & 7, l = (e >> 3) & 63, c = (e >> 9) & 7, q = e >> 12; // q in [0,32)
        int t = q & 1, w = q >> 1;
        int row = t * 256 + 16 * w + (l & 15);
        int kk = 32 * c + 8 * (l >> 4) + i;
        wfrag[e] = f2bf(W_hh[row * HB + kk]);
    }
    // n part: e in [0, 65536) at offset 131072
    for (int e = tid; e < HB * HB; e += stride) {
        int i = e & 7, l = (e >> 3) & 63, c = (e >> 9) & 7, w = e >> 12; // w in [0,16)
        int row = 512 + 16 * w + (l & 15);
        int kk = 32 * c + 8 * (l >> 4) + i;
        wfrag[2 * HB * HB + e] = f2bf(W_hh[row * HB + kk]);
    }
    if (do_wout) {
        for (int e = tid; e < NV * HB; e += stride) woutbf[e] = f2bf(W_out[e]);
    }
}

// ---------------------------------------------------------------- K1: embed + xp
__global__ __launch_bounds__(256) void k_embed_xp(
        const int* __restrict__ x, const float* __restrict__ emb,
        const float* __restrict__ w_ihT, const float* __restrict__ b_ih,
        const float* __restrict__ b_hh, float* __restrict__ xp) {
    __shared__ float e[8][HB];
    int tid = threadIdx.x;
    int tok0 = blockIdx.x * 8;
    {
        int s = tid >> 5, k0 = (tid & 31) * 8;
        long idx = x[tok0 + s];
        const float* src = emb + idx * (long)HB + k0;
        f32x4 a = *(const f32x4*)src, bq = *(const f32x4*)(src + 4);
        *(f32x4*)&e[s][k0] = a;
        *(f32x4*)&e[s][k0 + 4] = bq;
    }
    __syncthreads();
    #pragma unroll
    for (int it = 0; it < 3; ++it) {
        int gg = tid + it * 256;
        float acc[8] = {0.f, 0.f, 0.f, 0.f, 0.f, 0.f, 0.f, 0.f};
        for (int k = 0; k < HB; k += 4) {
            float w0 = w_ihT[(k + 0) * G3 + gg];
            float w1 = w_ihT[(k + 1) * G3 + gg];
            float w2 = w_ihT[(k + 2) * G3 + gg];
            float w3 = w_ihT[(k + 3) * G3 + gg];
            #pragma unroll
            for (int s = 0; s < 8; ++s) {
                f32x4 ev = *(const f32x4*)&e[s][k];
                acc[s] += w0 * ev.x + w1 * ev.y + w2 * ev.z + w3 * ev.w;
            }
        }
        float bias = b_ih[gg] + (gg < 512 ? b_hh[gg] : 0.f);
        #pragma unroll
        for (int s = 0; s < 8; ++s)
            xp[(size_t)(tok0 + s) * G3 + gg] = acc[s] + bias;
    }
}

// ---------------------------------------------------------------- K2: GRU scan
// One workgroup, 16 waves. Wave w owns hidden rows 16w..16w+15 for all 3 gates.
// r/z gate W in registers (A[2][8] = 64 VGPR); n gate W streamed from LDS
// (131 KB, ~1024 cyc/step, hidden under the 1862-cyc MFMA shadow). Two phases
// per step: (1) 24 MFMA -> hp LDS, (2) 1024-thread gate math -> h_bf + rnn.
// Peak regs ~107 < 128 cap (4 waves/SIMD) -> no spill.
__global__ __launch_bounds__(1024, 4) void k_gru(
        const float* __restrict__ xp, const unsigned short* __restrict__ wfrag,
        const float* __restrict__ b_hh, unsigned short* __restrict__ rnn) {
    extern __shared__ char smem[];
    unsigned short* wn = (unsigned short*)smem;                    // [16][8][64][8] 131072 B
    float (*hp)[784] = (float(*)[784])(smem + 131072);             // [4][784] 12544 B
    unsigned short* hbf = (unsigned short*)(smem + 143616);        // [2][4][256] 4096 B

    int tid = threadIdx.x;
    int w = tid >> 6, l = tid & 63;
    int c15 = l & 15, hi = l >> 4;
    int b4 = c15 & 3;

    // r/z A-fragments -> registers (lane-contiguous 16B global loads)
    bf16x8 Ar[8], Az[8];
    #pragma unroll
    for (int c = 0; c < 8; ++c) {
        Ar[c] = ((const bf16x8*)wfrag)[((w * 2 + 0) * 8 + c) * 64 + l];
        Az[c] = ((const bf16x8*)wfrag)[((w * 2 + 1) * 8 + c) * 64 + l];
    }
    // n-gate fragments -> LDS (65536 shorts)
    {
        const bf16x8* src = (const bf16x8*)(wfrag + 2 * HB * HB);
        bf16x8* dst = (bf16x8*)wn;
        #pragma unroll
        for (int it = 0; it < 8; ++it) dst[it * 1024 + tid] = src[it * 1024 + tid];
    }
    for (int k = tid; k < 2 * NBATCH * HB; k += 1024) hbf[k] = 0;

    // gate-thread identity: b = tid>>8, i = tid&255
    int gb = tid >> 8;
    int gi = tid & 255;
    float bn = b_hh[512 + gi];
    float hreg = 0.f;
    __syncthreads();

    const f32x4 zz = {0.f, 0.f, 0.f, 0.f};
    const char* hbase = (const char*)hbf;
    int boff = b4 * 512;                      // byte offset of batch row
    int hrow0 = 16 * w + 4 * hi;              // hp row base (gate 0)
    const unsigned short* wn_w = wn + w * 4096 + l * 8;

    for (int t = 0; t < SQ; ++t) {
        int cur = t & 1, nxt = cur ^ 1;
        // prefetch xp for phase 2 (in flight across the MFMA phase)
        const float* xpt = xp + ((size_t)gb * SQ + t) * G3 + gi;
        float xr = xpt[0], xz = xpt[256], xn = xpt[512];

        f32x4 acc0 = zz, acc1 = zz, acc2 = zz;
        const char* hb = hbase + cur * 2048 + boff;
        #pragma unroll
        for (int c = 0; c < 8; ++c) {
            int byteoff = (64 * c + 16 * hi) ^ ((c15 & 1) << 6);
            bf16x8 Bf = *(const bf16x8*)(hb + byteoff);
            bf16x8 An = *(const bf16x8*)(wn_w + c * 512);
            acc0 = __builtin_amdgcn_mfma_f32_16x16x32_bf16(Ar[c], Bf, acc0, 0, 0, 0);
            acc1 = __builtin_amdgcn_mfma_f32_16x16x32_bf16(Az[c], Bf, acc1, 0, 0, 0);
            acc2 = __builtin_amdgcn_mfma_f32_16x16x32_bf16(An,    Bf, acc2, 0, 0, 0);
        }
        if (c15 < 4) {
            *(f32x4*)&hp[c15][hrow0]       = acc0;
            *(f32x4*)&hp[c15][256 + hrow0] = acc1;
            *(f32x4*)&hp[c15][512 + hrow0] = acc2;
        }
        __syncthreads();

        // phase 2: gate math, fully parallel over (b,i)
        float r = sigm(xr + hp[gb][gi]);
        float z = sigm(xz + hp[gb][256 + gi]);
        float n = tanh_fast(xn + r * (hp[gb][512 + gi] + bn));
        float hv = (1.f - z) * n + z * hreg;
        hreg = hv;
        unsigned short h16 = f2bf(hv);
        *(unsigned short*)((char*)(hbf + nxt * 1024 + gb * 256) + ((gi * 2) ^ ((gb & 1) << 6))) = h16;
        rnn[((size_t)gb * SQ + t) * HB + gi] = h16;
        __syncthreads();
    }
}

// ---------------------------------------------------------------- K3: logits
// [2048,256] bf16 @ [256,32000] bf16 -> fp32 + bias + mask. No LDS: A (1 MB)
// and B (16 MB) are L2/L3 resident; HBM-write-bound.
template <int CONV>
__global__ __launch_bounds__(256) void k_logits(
        const unsigned short* __restrict__ rnn, const unsigned short* __restrict__ woutbf,
        const float* __restrict__ woutf, const float* __restrict__ b_out,
        const int* __restrict__ x, float* __restrict__ out) {
    int tid = threadIdx.x;
    int wv = tid >> 6, l = tid & 63;
    int wm = wv >> 1, wn = wv & 1;
    int c15 = l & 15, hi = l >> 4;
    int m0 = blockIdx.y * 128 + wm * 64;
    int n0 = blockIdx.x * 128 + wn * 64;

    const f32x4 zz = {0.f, 0.f, 0.f, 0.f};
    f32x4 acc[4][4];
    #pragma unroll
    for (int i = 0; i < 4; ++i)
        #pragma unroll
        for (int j = 0; j < 4; ++j) acc[i][j] = zz;

    #pragma unroll
    for (int c = 0; c < 8; ++c) {
        bf16x8 af[4], bfr[4];
        #pragma unroll
        for (int rt = 0; rt < 4; ++rt)
            af[rt] = *(const bf16x8*)(rnn + (size_t)(m0 + rt * 16 + c15) * HB + 32 * c + 8 * hi);
        #pragma unroll
        for (int ct = 0; ct < 4; ++ct) {
            if (CONV) {
                const float* s = woutf + (size_t)(n0 + ct * 16 + c15) * HB + 32 * c + 8 * hi;
                f32x4 lo = *(const f32x4*)s, hi4 = *(const f32x4*)(s + 4);
                bf16x8 bb;
                #pragma unroll
                for (int q = 0; q < 4; ++q) bb[q] = (short)f2bf(lo[q]);
                #pragma unroll
                for (int q = 0; q < 4; ++q) bb[4 + q] = (short)f2bf(hi4[q]);
                bfr[ct] = bb;
            } else {
                bfr[ct] = *(const bf16x8*)(woutbf + (size_t)(n0 + ct * 16 + c15) * HB + 32 * c + 8 * hi);
            }
        }
        #pragma unroll
        for (int rt = 0; rt < 4; ++rt)
            #pragma unroll
            for (int ct = 0; ct < 4; ++ct)
                acc[rt][ct] = __builtin_amdgcn_mfma_f32_16x16x32_bf16(af[rt], bfr[ct], acc[rt][ct], 0, 0, 0);
    }

    float bo[4];
    #pragma unroll
    for (int ct = 0; ct < 4; ++ct) bo[ct] = b_out[n0 + ct * 16 + c15];

    const float NEGINF = -__builtin_inff();
    #pragma unroll
    for (int rt = 0; rt < 4; ++rt) {
        #pragma unroll
        for (int j = 0; j < 4; ++j) {
            int m = m0 + rt * 16 + 4 * hi + j;
            int tt = m & (SQ - 1);
            bool bad = (tt > 0) && (x[m - 1] == 0);
            float* orow = out + (size_t)m * NV;
            #pragma unroll
            for (int ct = 0; ct < 4; ++ct) {
                int v = n0 + ct * 16 + c15;
                float val = acc[rt][ct][j] + bo[ct];
                if (bad && v >= 3) val = NEGINF;
                orow[v] = val;
            }
        }
    }
}

extern "C" void kernel_launch(void* const* d_in, const int* in_sizes, int n_in,
                              void* d_out, int out_size, void* d_ws, size_t ws_size,
                              hipStream_t stream) {
    const int*   x     = (const int*)d_in[0];
    const float* emb   = (const float*)d_in[1];
    const float* W_ih  = (const float*)d_in[2];
    const float* W_hh  = (const float*)d_in[3];
    const float* b_ih  = (const float*)d_in[4];
    const float* b_hh  = (const float*)d_in[5];
    const float* W_out = (const float*)d_in[6];
    const float* b_out = (const float*)d_in[7];
    float* out = (float*)d_out;

    char* ws = (char*)d_ws;
    float*          xp     = (float*)(ws);                       // 6,291,456 B
    float*          w_ihT  = (float*)(ws + 6291456);             // 786,432 B
    unsigned short* wfrag  = (unsigned short*)(ws + 7077888);    // 393,216 B
    unsigned short* rnn    = (unsigned short*)(ws + 7471104);    // 1,048,576 B
    unsigned short* woutbf = (unsigned short*)(ws + 8519680);    // 16,384,000 B
    int use_woutbf = (ws_size >= (size_t)24903680) ? 1 : 0;

    static int attr_done = 0;
    if (!attr_done) {
        hipFuncSetAttribute((const void*)k_gru,
                            hipFuncAttributeMaxDynamicSharedMemorySize, GRU_LDS_BYTES);
        attr_done = 1;
    }

    k_prep<<<2048, 256, 0, stream>>>(W_ih, W_hh, W_out, w_ihT, wfrag, woutbf, use_woutbf);
    k_embed_xp<<<256, 256, 0, stream>>>(x, emb, w_ihT, b_ih, b_hh, xp);
    k_gru<<<1, 1024, GRU_LDS_BYTES, stream>>>(xp, wfrag, b_hh, rnn);
    dim3 g3(NV / 128, 2048 / 128);
    if (use_woutbf)
        k_logits<0><<<g3, 256, 0, stream>>>(rnn, woutbf, nullptr, b_out, x, out);
    else
        k_logits<1><<<g3, 256, 0, stream>>>(rnn, nullptr, W_out, b_out, x, out);
}

// Round 4
// 992.793 us; speedup vs baseline: 1.8120x; 1.0031x over previous
//
#include <hip/hip_runtime.h>
#include <hip/hip_bf16.h>

typedef __attribute__((ext_vector_type(8))) short bf16x8;
typedef __attribute__((ext_vector_type(4))) float f32x4;
typedef __attribute__((ext_vector_type(4))) unsigned short u16x4;

#define HB 256      // hidden
#define G3 768      // 3*H
#define SQ 512      // seq len
#define NBATCH 4
#define NV 32000

__device__ __forceinline__ unsigned short f2bf(float f) {
    unsigned int u = __float_as_uint(f);
    u = u + 0x7FFFu + ((u >> 16) & 1u);   // RNE
    return (unsigned short)(u >> 16);
}
__device__ __forceinline__ float sigm(float x) {
    return 1.0f / (1.0f + __expf(-x));
}
__device__ __forceinline__ float tanh_fast(float x) {
    // safe at +/-inf: 1 - 2/(e^{2x}+1)
    return 1.0f - 2.0f / (__expf(2.0f * x) + 1.0f);
}

// ---------------------------------------------------------------- K0: prep
// (a) W_ih^T fp32 [256][768] for coalesced K1 loads
// (b) W_hh -> bf16 MFMA A-fragments for the 8-wave k_gru:
//     layout [w:8][t:3][rt:2][c:8][lane:64][i:8]
//     wave w owns hidden rows 32w..32w+31 (two 16-row tiles rt) per gate t
// (c) W_out -> bf16 (optional, if ws large enough)
__global__ void k_prep(const float* __restrict__ W_ih, const float* __restrict__ W_hh,
                       const float* __restrict__ W_out, float* __restrict__ w_ihT,
                       unsigned short* __restrict__ wfrag, unsigned short* __restrict__ woutbf,
                       int do_wout) {
    int stride = gridDim.x * blockDim.x;
    int tid = blockIdx.x * blockDim.x + threadIdx.x;
    for (int e = tid; e < G3 * HB; e += stride) {
        int k = e / G3, g = e - k * G3;
        w_ihT[e] = W_ih[g * HB + k];
    }
    for (int e = tid; e < G3 * HB; e += stride) {
        int i = e & 7, l = (e >> 3) & 63, c = (e >> 9) & 7, rt = (e >> 12) & 1;
        int q = e >> 13;              // 0..23
        int t = q % 3, w = q / 3;     // gate, wave
        int row = t * 256 + 32 * w + 16 * rt + (l & 15);
        int kk = 32 * c + 8 * (l >> 4) + i;
        wfrag[e] = f2bf(W_hh[row * HB + kk]);
    }
    if (do_wout) {
        for (int e = tid; e < NV * HB; e += stride) woutbf[e] = f2bf(W_out[e]);
    }
}

// ---------------------------------------------------------------- K1: embed + xp
__global__ __launch_bounds__(256) void k_embed_xp(
        const int* __restrict__ x, const float* __restrict__ emb,
        const float* __restrict__ w_ihT, const float* __restrict__ b_ih,
        const float* __restrict__ b_hh, float* __restrict__ xp) {
    __shared__ float e[8][HB];
    int tid = threadIdx.x;
    int tok0 = blockIdx.x * 8;
    {
        int s = tid >> 5, k0 = (tid & 31) * 8;
        long idx = x[tok0 + s];
        const float* src = emb + idx * (long)HB + k0;
        f32x4 a = *(const f32x4*)src, bq = *(const f32x4*)(src + 4);
        *(f32x4*)&e[s][k0] = a;
        *(f32x4*)&e[s][k0 + 4] = bq;
    }
    __syncthreads();
    #pragma unroll
    for (int it = 0; it < 3; ++it) {
        int gg = tid + it * 256;
        float acc[8] = {0.f, 0.f, 0.f, 0.f, 0.f, 0.f, 0.f, 0.f};
        for (int k = 0; k < HB; k += 4) {
            float w0 = w_ihT[(k + 0) * G3 + gg];
            float w1 = w_ihT[(k + 1) * G3 + gg];
            float w2 = w_ihT[(k + 2) * G3 + gg];
            float w3 = w_ihT[(k + 3) * G3 + gg];
            #pragma unroll
            for (int s = 0; s < 8; ++s) {
                f32x4 ev = *(const f32x4*)&e[s][k];
                acc[s] += w0 * ev.x + w1 * ev.y + w2 * ev.z + w3 * ev.w;
            }
        }
        float bias = b_ih[gg] + (gg < 512 ? b_hh[gg] : 0.f);
        #pragma unroll
        for (int s = 0; s < 8; ++s)
            xp[(size_t)(tok0 + s) * G3 + gg] = acc[s] + bias;
    }
}

// ---------------------------------------------------------------- K2: GRU scan
// One workgroup, 8 waves (512 thr), 2 waves/SIMD -> 256-VGPR budget via
// amdgpu_waves_per_eu(2,2). Wave w owns hidden rows 32w..32w+31 for all 3
// gates: A[3][2][8] bf16 fragments = 192 VGPR, pinned with asm so they can't
// be rematerialized from global. Per step:
//   phase 1: 48 MFMA/wave (384 total = 466 cyc/SIMD) + 8 ds_read_b128/wave
//            for h B-frags (64 KB/step total) -> hp LDS
//   phase 2: 512 threads x 2 (batch,i) items: gate math -> h_bf + rnn
__global__ __attribute__((amdgpu_waves_per_eu(2, 2))) __launch_bounds__(512)
void k_gru(const float* __restrict__ xp, const unsigned short* __restrict__ wfrag,
           const float* __restrict__ b_hh, unsigned short* __restrict__ rnn) {
    __shared__ float hp[NBATCH][784];                // 12544 B (pad: 784)
    __shared__ unsigned short hbf[2][NBATCH][HB];    // 4096 B, XOR-swizzled

    int tid = threadIdx.x;
    int w = tid >> 6, l = tid & 63;
    int c15 = l & 15, hi = l >> 4;
    int b4 = c15 & 3;

    // 48 A-fragments -> registers (lane-contiguous 16B global loads)
    bf16x8 A[3][2][8];
    #pragma unroll
    for (int t3 = 0; t3 < 3; ++t3)
        #pragma unroll
        for (int rt = 0; rt < 2; ++rt)
            #pragma unroll
            for (int c = 0; c < 8; ++c)
                A[t3][rt][c] = ((const bf16x8*)wfrag)[(((w * 3 + t3) * 2 + rt) * 8 + c) * 64 + l];
    // pin: forbid rematerialization-from-global of the fragments
    #pragma unroll
    for (int t3 = 0; t3 < 3; ++t3)
        #pragma unroll
        for (int rt = 0; rt < 2; ++rt)
            #pragma unroll
            for (int c = 0; c < 8; ++c)
                asm volatile("" : "+v"(A[t3][rt][c]));

    // gate-item identity: item0 = (b0, i), item1 = (b0+2, i)
    int i256 = tid & 255;
    int b0 = tid >> 8;                // 0 or 1
    float bn = b_hh[512 + i256];
    float h0 = 0.f, h1 = 0.f;

    for (int k = tid; k < 2 * NBATCH * HB; k += 512) ((unsigned short*)hbf)[k] = 0;
    __syncthreads();

    const f32x4 zz = {0.f, 0.f, 0.f, 0.f};
    const char* hbase = (const char*)hbf;
    int boff = b4 * 512;              // byte offset of batch row in hbf
    int hrow0 = 32 * w + 4 * hi;      // hp row base (gate 0, rt 0)

    for (int t = 0; t < SQ; ++t) {
        int cur = t & 1, nxt = cur ^ 1;
        // prefetch xp for phase 2 (latency hides under phase 1)
        const float* xp0 = xp + ((size_t)b0 * SQ + t) * G3 + i256;
        const float* xp1 = xp + ((size_t)(b0 + 2) * SQ + t) * G3 + i256;
        float xr0 = xp0[0], xz0 = xp0[256], xn0 = xp0[512];
        float xr1 = xp1[0], xz1 = xp1[256], xn1 = xp1[512];

        f32x4 acc[3][2];
        #pragma unroll
        for (int t3 = 0; t3 < 3; ++t3) { acc[t3][0] = zz; acc[t3][1] = zz; }

        const char* hb = hbase + cur * 2048 + boff;
        #pragma unroll
        for (int c = 0; c < 8; ++c) {
            int byteoff = (64 * c + 16 * hi) ^ ((c15 & 1) << 6);
            bf16x8 Bf = *(const bf16x8*)(hb + byteoff);
            #pragma unroll
            for (int t3 = 0; t3 < 3; ++t3) {
                acc[t3][0] = __builtin_amdgcn_mfma_f32_16x16x32_bf16(A[t3][0][c], Bf, acc[t3][0], 0, 0, 0);
                acc[t3][1] = __builtin_amdgcn_mfma_f32_16x16x32_bf16(A[t3][1][c], Bf, acc[t3][1], 0, 0, 0);
            }
        }
        if (c15 < 4) {
            #pragma unroll
            for (int t3 = 0; t3 < 3; ++t3) {
                *(f32x4*)&hp[c15][t3 * 256 + hrow0]      = acc[t3][0];
                *(f32x4*)&hp[c15][t3 * 256 + hrow0 + 16] = acc[t3][1];
            }
        }
        __syncthreads();

        // phase 2: gate math, 2 items per thread
        {
            float r = sigm(xr0 + hp[b0][i256]);
            float z = sigm(xz0 + hp[b0][256 + i256]);
            float n = tanh_fast(xn0 + r * (hp[b0][512 + i256] + bn));
            float hv = (1.f - z) * n + z * h0;
            h0 = hv;
            unsigned short h16 = f2bf(hv);
            *(unsigned short*)((char*)hbf + nxt * 2048 + b0 * 512 + ((i256 * 2) ^ ((b0 & 1) << 6))) = h16;
            rnn[((size_t)b0 * SQ + t) * HB + i256] = h16;
        }
        {
            int b1 = b0 + 2;
            float r = sigm(xr1 + hp[b1][i256]);
            float z = sigm(xz1 + hp[b1][256 + i256]);
            float n = tanh_fast(xn1 + r * (hp[b1][512 + i256] + bn));
            float hv = (1.f - z) * n + z * h1;
            h1 = hv;
            unsigned short h16 = f2bf(hv);
            *(unsigned short*)((char*)hbf + nxt * 2048 + b1 * 512 + ((i256 * 2) ^ ((b1 & 1) << 6))) = h16;
            rnn[((size_t)b1 * SQ + t) * HB + i256] = h16;
        }
        __syncthreads();
    }
}

// ---------------------------------------------------------------- K3: logits
// [2048,256] bf16 @ [256,32000] bf16 -> fp32 + bias + mask. No LDS: A (1 MB)
// and B (16 MB) are L2/L3 resident; HBM-write-bound.
template <int CONV>
__global__ __launch_bounds__(256) void k_logits(
        const unsigned short* __restrict__ rnn, const unsigned short* __restrict__ woutbf,
        const float* __restrict__ woutf, const float* __restrict__ b_out,
        const int* __restrict__ x, float* __restrict__ out) {
    int tid = threadIdx.x;
    int wv = tid >> 6, l = tid & 63;
    int wm = wv >> 1, wn = wv & 1;
    int c15 = l & 15, hi = l >> 4;
    int m0 = blockIdx.y * 128 + wm * 64;
    int n0 = blockIdx.x * 128 + wn * 64;

    const f32x4 zz = {0.f, 0.f, 0.f, 0.f};
    f32x4 acc[4][4];
    #pragma unroll
    for (int i = 0; i < 4; ++i)
        #pragma unroll
        for (int j = 0; j < 4; ++j) acc[i][j] = zz;

    #pragma unroll
    for (int c = 0; c < 8; ++c) {
        bf16x8 af[4], bfr[4];
        #pragma unroll
        for (int rt = 0; rt < 4; ++rt)
            af[rt] = *(const bf16x8*)(rnn + (size_t)(m0 + rt * 16 + c15) * HB + 32 * c + 8 * hi);
        #pragma unroll
        for (int ct = 0; ct < 4; ++ct) {
            if (CONV) {
                const float* s = woutf + (size_t)(n0 + ct * 16 + c15) * HB + 32 * c + 8 * hi;
                f32x4 lo = *(const f32x4*)s, hi4 = *(const f32x4*)(s + 4);
                bf16x8 bb;
                #pragma unroll
                for (int q = 0; q < 4; ++q) bb[q] = (short)f2bf(lo[q]);
                #pragma unroll
                for (int q = 0; q < 4; ++q) bb[4 + q] = (short)f2bf(hi4[q]);
                bfr[ct] = bb;
            } else {
                bfr[ct] = *(const bf16x8*)(woutbf + (size_t)(n0 + ct * 16 + c15) * HB + 32 * c + 8 * hi);
            }
        }
        #pragma unroll
        for (int rt = 0; rt < 4; ++rt)
            #pragma unroll
            for (int ct = 0; ct < 4; ++ct)
                acc[rt][ct] = __builtin_amdgcn_mfma_f32_16x16x32_bf16(af[rt], bfr[ct], acc[rt][ct], 0, 0, 0);
    }

    float bo[4];
    #pragma unroll
    for (int ct = 0; ct < 4; ++ct) bo[ct] = b_out[n0 + ct * 16 + c15];

    const float NEGINF = -__builtin_inff();
    #pragma unroll
    for (int rt = 0; rt < 4; ++rt) {
        #pragma unroll
        for (int j = 0; j < 4; ++j) {
            int m = m0 + rt * 16 + 4 * hi + j;
            int tt = m & (SQ - 1);
            bool bad = (tt > 0) && (x[m - 1] == 0);
            float* orow = out + (size_t)m * NV;
            #pragma unroll
            for (int ct = 0; ct < 4; ++ct) {
                int v = n0 + ct * 16 + c15;
                float val = acc[rt][ct][j] + bo[ct];
                if (bad && v >= 3) val = NEGINF;
                orow[v] = val;
            }
        }
    }
}

extern "C" void kernel_launch(void* const* d_in, const int* in_sizes, int n_in,
                              void* d_out, int out_size, void* d_ws, size_t ws_size,
                              hipStream_t stream) {
    const int*   x     = (const int*)d_in[0];
    const float* emb   = (const float*)d_in[1];
    const float* W_ih  = (const float*)d_in[2];
    const float* W_hh  = (const float*)d_in[3];
    const float* b_ih  = (const float*)d_in[4];
    const float* b_hh  = (const float*)d_in[5];
    const float* W_out = (const float*)d_in[6];
    const float* b_out = (const float*)d_in[7];
    float* out = (float*)d_out;

    char* ws = (char*)d_ws;
    float*          xp     = (float*)(ws);                       // 6,291,456 B
    float*          w_ihT  = (float*)(ws + 6291456);             // 786,432 B
    unsigned short* wfrag  = (unsigned short*)(ws + 7077888);    // 393,216 B
    unsigned short* rnn    = (unsigned short*)(ws + 7471104);    // 1,048,576 B
    unsigned short* woutbf = (unsigned short*)(ws + 8519680);    // 16,384,000 B
    int use_woutbf = (ws_size >= (size_t)24903680) ? 1 : 0;

    k_prep<<<2048, 256, 0, stream>>>(W_ih, W_hh, W_out, w_ihT, wfrag, woutbf, use_woutbf);
    k_embed_xp<<<256, 256, 0, stream>>>(x, emb, w_ihT, b_ih, b_hh, xp);
    k_gru<<<1, 512, 0, stream>>>(xp, wfrag, b_hh, rnn);
    dim3 g3(NV / 128, 2048 / 128);
    if (use_woutbf)
        k_logits<0><<<g3, 256, 0, stream>>>(rnn, woutbf, nullptr, b_out, x, out);
    else
        k_logits<1><<<g3, 256, 0, stream>>>(rnn, nullptr, W_out, b_out, x, out);
}